// Round 2
// baseline (109149.072 us; speedup 1.0000x reference)
//
#include <hip/hip_runtime.h>
#include <hip/hip_bf16.h>

// Problem constants (EncoderRNN: V=29, H=1024, L=4, B=64, S=512)
#define Vn 29
#define Hn 1024
#define Ln 4
#define Bn 64
#define Sn 512
#define G4 (4 * Hn)      // 4096 gate rows per layer
#define BH (Bn * Hn)     // 65536
#define LBH (Ln * BH)    // 262144

typedef __attribute__((ext_vector_type(8))) short bf16x8;  // 8 bf16 = 4 VGPRs
typedef __attribute__((ext_vector_type(4))) float f32x4;

__device__ __forceinline__ float sigmf(float x) { return 1.0f / (1.0f + __expf(-x)); }
__device__ __forceinline__ float tanhf_(float x) { return 1.0f - 2.0f / (__expf(2.0f * x) + 1.0f); }

// ---------------------------------------------------------------------------
// Dtype detection: are float inputs bf16 or float32?
// Look at w_ih (uniform +-1/32). If data is bf16, the low 16 bits of each
// dword are a real weight: bf16 exponent field in [0x60, 0x7A] (~100% pass).
// If data is float32, the low 16 bits are mantissa randomness (~10% pass).
__global__ void detect_kernel(const unsigned* __restrict__ wih_raw, int* __restrict__ flag) {
    __shared__ int cnt;
    if (threadIdx.x == 0) cnt = 0;
    __syncthreads();
    int local = 0;
    for (int i = 0; i < 16; ++i) {
        unsigned v = wih_raw[threadIdx.x * 16 + i];
        unsigned lo = v & 0xFFFFu;
        unsigned e = (lo >> 7) & 0xFFu;
        if ((e >= 0x60u && e <= 0x7Au) || ((lo & 0x7FFFu) == 0u)) local++;
    }
    atomicAdd(&cnt, local);
    __syncthreads();
    if (threadIdx.x == 0) flag[0] = (cnt >= 2048) ? 1 : 0;  // 1 = bf16 source
}

// Zero state, combine biases to fp32, split embedding into hi/lo bf16 planes.
__global__ void init_kernel(const int* __restrict__ flag, const void* __restrict__ emb_raw,
                            const void* __restrict__ bi_raw, const void* __restrict__ bh_raw,
                            float* __restrict__ hf, float* __restrict__ cf,
                            __hip_bfloat16* __restrict__ hbhi, __hip_bfloat16* __restrict__ hblo,
                            float* __restrict__ biasf,
                            __hip_bfloat16* __restrict__ ehi, __hip_bfloat16* __restrict__ elo) {
    const int isbf = flag[0];
    int i = blockIdx.x * blockDim.x + threadIdx.x;
    int stride = gridDim.x * blockDim.x;
    for (int k = i; k < LBH; k += stride) { hf[k] = 0.f; cf[k] = 0.f; }
    const __hip_bfloat16 z = __float2bfloat16(0.f);
    for (int k = i; k < 2 * LBH; k += stride) { hbhi[k] = z; hblo[k] = z; }
    for (int k = i; k < Ln * G4; k += stride) {
        float bi = isbf ? __bfloat162float(((const __hip_bfloat16*)bi_raw)[k]) : ((const float*)bi_raw)[k];
        float bh = isbf ? __bfloat162float(((const __hip_bfloat16*)bh_raw)[k]) : ((const float*)bh_raw)[k];
        biasf[k] = bi + bh;
    }
    for (int k = i; k < Vn * Hn; k += stride) {
        float e = 0.f;
        if (k >= Hn)  // padding_idx row 0 stays zero
            e = isbf ? __bfloat162float(((const __hip_bfloat16*)emb_raw)[k]) : ((const float*)emb_raw)[k];
        __hip_bfloat16 hi = __float2bfloat16(e);
        ehi[k] = hi;
        elo[k] = __float2bfloat16(e - __bfloat162float(hi));
    }
}

// One LSTM cell (timestep t, layer l). Grid: 64 WGs x 256 threads.
// WG n owns hidden units [16n,16n+16) => 64 gate rows (i,f,g,o x 16).
// Wave w owns batch tile w x all 4 gate tiles => pointwise update is in-wave.
// Numerics: hi/lo bf16 split of A (activations) and W => fp32-faithful gates.
__global__ __launch_bounds__(256) void lstm_cell_kernel(
    const int* __restrict__ padded_in, const int* __restrict__ in_lengths,
    const int* __restrict__ flag,
    const void* __restrict__ wih_raw, const void* __restrict__ whh_raw,
    const float* __restrict__ biasf,
    const __hip_bfloat16* __restrict__ ehi, const __hip_bfloat16* __restrict__ elo,
    __hip_bfloat16* __restrict__ ybhi, __hip_bfloat16* __restrict__ yblo,
    __hip_bfloat16* __restrict__ hbhi, __hip_bfloat16* __restrict__ hblo,
    float* __restrict__ hf, float* __restrict__ cf, int t, int l) {
    // +8 bf16 pad => 144B row stride => only 2-way LDS bank aliasing (free)
    __shared__ __align__(16) __hip_bfloat16 lAhi[64][72];
    __shared__ __align__(16) __hip_bfloat16 lAlo[64][72];
    __shared__ __align__(16) __hip_bfloat16 lWhi[64][72];
    __shared__ __align__(16) __hip_bfloat16 lWlo[64][72];

    const int isbf = flag[0];
    const int tid = threadIdx.x;
    const int wave = tid >> 6;
    const int lane = tid & 63;
    const int j0 = blockIdx.x * 16;
    const int pin = t & 1;
    const int pout = pin ^ 1;
    const int bs = in_lengths[t];

    const int srow = tid >> 2;         // staging row 0..63
    const int scol = (tid & 3) * 16;   // staging col chunk (16 elements)

    // W row for staging: gate = srow>>4, unit = j0 + (srow&15)
    const int wrow = (srow >> 4) * Hn + j0 + (srow & 15);
    const size_t woff = ((size_t)l * G4 + wrow) * Hn;

    // A sources (split bf16 planes)
    const __hip_bfloat16 *ayhi, *aylo;
    if (l == 0) {
        int idx = padded_in[srow * Sn + t];
        ayhi = ehi + (size_t)idx * Hn;
        aylo = elo + (size_t)idx * Hn;
    } else {
        ayhi = ybhi + (size_t)(l & 1) * BH + srow * Hn;
        aylo = yblo + (size_t)(l & 1) * BH + srow * Hn;
    }
    const size_t hoff = ((size_t)(pin * Ln + l) * Bn + srow) * Hn;
    const __hip_bfloat16* ahhi = hbhi + hoff;
    const __hip_bfloat16* ahlo = hblo + hoff;

    f32x4 acc[4];
#pragma unroll
    for (int g = 0; g < 4; ++g) acc[g] = (f32x4){0.f, 0.f, 0.f, 0.f};

    const int frow = lane & 15;
    const int fcol = (lane >> 4) * 8;

    for (int kc = 0; kc < 32; ++kc) {
        const int k0 = kc * 64;
        const bool first = (k0 < Hn);
        const int kw = first ? k0 : (k0 - Hn);
        const __hip_bfloat16* Ah = (first ? ayhi : ahhi) + kw;
        const __hip_bfloat16* Al = (first ? aylo : ahlo) + kw;

        *reinterpret_cast<float4*>(&lAhi[srow][scol]) = *reinterpret_cast<const float4*>(Ah + scol);
        *reinterpret_cast<float4*>(&lAhi[srow][scol + 8]) = *reinterpret_cast<const float4*>(Ah + scol + 8);
        *reinterpret_cast<float4*>(&lAlo[srow][scol]) = *reinterpret_cast<const float4*>(Al + scol);
        *reinterpret_cast<float4*>(&lAlo[srow][scol + 8]) = *reinterpret_cast<const float4*>(Al + scol + 8);

        if (isbf) {
            const __hip_bfloat16* Wsrc =
                (const __hip_bfloat16*)(first ? wih_raw : whh_raw) + woff + kw;
            *reinterpret_cast<float4*>(&lWhi[srow][scol]) = *reinterpret_cast<const float4*>(Wsrc + scol);
            *reinterpret_cast<float4*>(&lWhi[srow][scol + 8]) = *reinterpret_cast<const float4*>(Wsrc + scol + 8);
        } else {
            const float* Wsrc = (const float*)(first ? wih_raw : whh_raw) + woff + kw;
            float wv[16];
            *reinterpret_cast<float4*>(&wv[0]) = *reinterpret_cast<const float4*>(Wsrc + scol);
            *reinterpret_cast<float4*>(&wv[4]) = *reinterpret_cast<const float4*>(Wsrc + scol + 4);
            *reinterpret_cast<float4*>(&wv[8]) = *reinterpret_cast<const float4*>(Wsrc + scol + 8);
            *reinterpret_cast<float4*>(&wv[12]) = *reinterpret_cast<const float4*>(Wsrc + scol + 12);
            union { __hip_bfloat16 b[16]; float4 f[2]; } uh, ul;
#pragma unroll
            for (int e = 0; e < 16; ++e) {
                __hip_bfloat16 hi = __float2bfloat16(wv[e]);
                uh.b[e] = hi;
                ul.b[e] = __float2bfloat16(wv[e] - __bfloat162float(hi));
            }
            *reinterpret_cast<float4*>(&lWhi[srow][scol]) = uh.f[0];
            *reinterpret_cast<float4*>(&lWhi[srow][scol + 8]) = uh.f[1];
            *reinterpret_cast<float4*>(&lWlo[srow][scol]) = ul.f[0];
            *reinterpret_cast<float4*>(&lWlo[srow][scol + 8]) = ul.f[1];
        }
        __syncthreads();

#pragma unroll
        for (int kk = 0; kk < 2; ++kk) {
            bf16x8 ahi = *reinterpret_cast<const bf16x8*>(&lAhi[wave * 16 + frow][kk * 32 + fcol]);
            bf16x8 alo = *reinterpret_cast<const bf16x8*>(&lAlo[wave * 16 + frow][kk * 32 + fcol]);
#pragma unroll
            for (int g = 0; g < 4; ++g) {
                bf16x8 wh = *reinterpret_cast<const bf16x8*>(&lWhi[g * 16 + frow][kk * 32 + fcol]);
                acc[g] = __builtin_amdgcn_mfma_f32_16x16x32_bf16(ahi, wh, acc[g], 0, 0, 0);
                acc[g] = __builtin_amdgcn_mfma_f32_16x16x32_bf16(alo, wh, acc[g], 0, 0, 0);
            }
            if (!isbf) {
#pragma unroll
                for (int g = 0; g < 4; ++g) {
                    bf16x8 wl = *reinterpret_cast<const bf16x8*>(&lWlo[g * 16 + frow][kk * 32 + fcol]);
                    acc[g] = __builtin_amdgcn_mfma_f32_16x16x32_bf16(ahi, wl, acc[g], 0, 0, 0);
                }
            }
        }
        __syncthreads();
    }

    // Epilogue: D[m][n]: n = lane&15 (unit col), m = (lane>>4)*4 + r (batch)
    const int j = j0 + frow;
    float bias[4];
#pragma unroll
    for (int g = 0; g < 4; ++g) bias[g] = biasf[l * G4 + g * Hn + j];

#pragma unroll
    for (int r = 0; r < 4; ++r) {
        const int b = wave * 16 + (lane >> 4) * 4 + r;
        const int sidx = (l * Bn + b) * Hn + j;
        float c_old = cf[sidx];
        float h_old = hf[sidx];
        float gi = acc[0][r] + bias[0];
        float gf = acc[1][r] + bias[1];
        float gg = acc[2][r] + bias[2];
        float go = acc[3][r] + bias[3];
        float c_new = sigmf(gf) * c_old + sigmf(gi) * tanhf_(gg);
        float h_new = sigmf(go) * tanhf_(c_new);
        const bool active = (b < bs);
        float c_sel = active ? c_new : c_old;
        float h_sel = active ? h_new : h_old;
        cf[sidx] = c_sel;
        hf[sidx] = h_sel;
        const size_t ho = ((size_t)(pout * Ln + l) * Bn + b) * Hn + j;
        __hip_bfloat16 hh = __float2bfloat16(h_sel);
        hbhi[ho] = hh;
        hblo[ho] = __float2bfloat16(h_sel - __bfloat162float(hh));
        if (l < Ln - 1) {
            float y_old;
            if (l == 0) {
                int idx = padded_in[b * Sn + t];
                y_old = __bfloat162float(ehi[(size_t)idx * Hn + j]) +
                        __bfloat162float(elo[(size_t)idx * Hn + j]);
            } else {
                const size_t yo = (size_t)(l & 1) * BH + b * Hn + j;
                y_old = __bfloat162float(ybhi[yo]) + __bfloat162float(yblo[yo]);
            }
            float y_sel = active ? (h_new + h_old) : y_old;
            const size_t yo2 = (size_t)((l + 1) & 1) * BH + b * Hn + j;
            __hip_bfloat16 yh = __float2bfloat16(y_sel);
            ybhi[yo2] = yh;
            yblo[yo2] = __float2bfloat16(y_sel - __bfloat162float(yh));
        }
    }
}

__global__ void write_out_kernel(const int* __restrict__ flag, const float* __restrict__ hf,
                                 void* __restrict__ out) {
    int i = blockIdx.x * blockDim.x + threadIdx.x;
    if (i >= BH) return;
    float v = hf[(size_t)(Ln - 1) * BH + i];
    if (flag[0]) ((__hip_bfloat16*)out)[i] = __float2bfloat16(v);
    else ((float*)out)[i] = v;
}

extern "C" void kernel_launch(void* const* d_in, const int* in_sizes, int n_in,
                              void* d_out, int out_size, void* d_ws, size_t ws_size,
                              hipStream_t stream) {
    const int* padded_in = (const int*)d_in[0];
    const int* in_lengths = (const int*)d_in[1];
    const void* emb_raw = d_in[2];
    const void* wih_raw = d_in[3];
    const void* whh_raw = d_in[4];
    const void* bi_raw = d_in[5];
    const void* bh_raw = d_in[6];

    // workspace layout (~4.8 MB)
    char* w = (char*)d_ws;
    int* flag = (int*)w;                         w += 256;
    float* biasf = (float*)w;                    w += (size_t)Ln * G4 * 4;
    float* hf = (float*)w;                       w += (size_t)LBH * 4;
    float* cf = (float*)w;                       w += (size_t)LBH * 4;
    __hip_bfloat16* ehi = (__hip_bfloat16*)w;    w += (size_t)Vn * Hn * 2;
    __hip_bfloat16* elo = (__hip_bfloat16*)w;    w += (size_t)Vn * Hn * 2;
    __hip_bfloat16* hbhi = (__hip_bfloat16*)w;   w += (size_t)2 * LBH * 2;
    __hip_bfloat16* hblo = (__hip_bfloat16*)w;   w += (size_t)2 * LBH * 2;
    __hip_bfloat16* ybhi = (__hip_bfloat16*)w;   w += (size_t)2 * BH * 2;
    __hip_bfloat16* yblo = (__hip_bfloat16*)w;   w += (size_t)2 * BH * 2;

    detect_kernel<<<1, 256, 0, stream>>>((const unsigned*)wih_raw, flag);
    init_kernel<<<512, 256, 0, stream>>>(flag, emb_raw, bi_raw, bh_raw,
                                         hf, cf, hbhi, hblo, biasf, ehi, elo);
    for (int t = 0; t < Sn; ++t)
        for (int l = 0; l < Ln; ++l)
            lstm_cell_kernel<<<64, 256, 0, stream>>>(padded_in, in_lengths, flag,
                                                     wih_raw, whh_raw, biasf, ehi, elo,
                                                     ybhi, yblo, hbhi, hblo, hf, cf, t, l);
    write_out_kernel<<<256, 256, 0, stream>>>(flag, hf, d_out);
}

// Round 4
// 24901.059 us; speedup vs baseline: 4.3833x; 4.3833x over previous
//
#include <hip/hip_runtime.h>
#include <hip/hip_fp16.h>

// EncoderRNN: V=29, H=1024, L=4, B=64, S=512. Inputs/out are FLOAT32 (proven R1/R2).
#define Vn 29
#define Hn 1024
#define Ln 4
#define Bn 64
#define Sn 512
#define NBLK 256

typedef _Float16 half8 __attribute__((ext_vector_type(8)));
typedef _Float16 half4v __attribute__((ext_vector_type(4)));
typedef float f32x16 __attribute__((ext_vector_type(16)));
typedef float f32x4 __attribute__((ext_vector_type(4)));

__device__ __forceinline__ float sigmf(float x) { return 1.0f / (1.0f + __expf(-x)); }
__device__ __forceinline__ float tanhf_(float x) { return 1.0f - 2.0f / (__expf(2.0f * x) + 1.0f); }

// barrier block: c0[8] padded 32 ints apart (0..255), c1 at [256], gen at [288]
#define BAR_INTS 320

__global__ void init_kernel(const float* __restrict__ bi, const float* __restrict__ bh,
                            const float* __restrict__ emb, int* __restrict__ bar,
                            float* __restrict__ biasf,
                            _Float16* __restrict__ ehi, _Float16* __restrict__ elo,
                            _Float16* __restrict__ hbhi, _Float16* __restrict__ hblo) {
    int i = blockIdx.x * blockDim.x + threadIdx.x;
    int stride = gridDim.x * blockDim.x;
    for (int k = i; k < BAR_INTS; k += stride) bar[k] = 0;
    for (int k = i; k < Ln * 4 * Hn; k += stride) biasf[k] = bi[k] + bh[k];
    for (int k = i; k < Vn * Hn; k += stride) {
        float e = (k < Hn) ? 0.f : emb[k];  // padding_idx=0 row zero
        _Float16 h = (_Float16)e;
        ehi[k] = h;
        elo[k] = (_Float16)(e - (float)h);
    }
    for (int k = i; k < 2 * Ln * Bn * Hn; k += stride) {
        hbhi[k] = (_Float16)0.f;
        hblo[k] = (_Float16)0.f;
    }
}

// Two-level sense/generation grid barrier, agent scope (cross-XCD safe).
// Reset-before-release; clock64 escape turns a co-residency failure into a
// clean wrong-answer instead of a harness hang.
__device__ __forceinline__ void grid_barrier(int* __restrict__ bar, int bid) {
    __syncthreads();
    if (threadIdx.x == 0) {
        int* c0 = bar + (bid & 7) * 32;
        int* c1 = bar + 256;
        int* gen = bar + 288;
        int my = __hip_atomic_load(gen, __ATOMIC_RELAXED, __HIP_MEMORY_SCOPE_AGENT);
        bool releaser = false;
        int p = __hip_atomic_fetch_add(c0, 1, __ATOMIC_ACQ_REL, __HIP_MEMORY_SCOPE_AGENT);
        if (p == 31) {
            int q = __hip_atomic_fetch_add(c1, 1, __ATOMIC_ACQ_REL, __HIP_MEMORY_SCOPE_AGENT);
            if (q == 7) {
                for (int g = 0; g < 8; ++g)
                    __hip_atomic_store(bar + g * 32, 0, __ATOMIC_RELAXED, __HIP_MEMORY_SCOPE_AGENT);
                __hip_atomic_store(c1, 0, __ATOMIC_RELAXED, __HIP_MEMORY_SCOPE_AGENT);
                __hip_atomic_store(gen, my + 1, __ATOMIC_RELEASE, __HIP_MEMORY_SCOPE_AGENT);
                releaser = true;
            }
        }
        if (!releaser) {
            long long t0 = clock64();
            while (__hip_atomic_load(gen, __ATOMIC_ACQUIRE, __HIP_MEMORY_SCOPE_AGENT) == my) {
                __builtin_amdgcn_s_sleep(2);
                if (clock64() - t0 > 2000000000LL) break;  // ~0.85 s escape hatch
            }
        }
    }
    __syncthreads();
}

// MFMA phase for one cell: MT batch-tiles of 32, 2 gate-row tiles, K-slice 512/wave.
// gates += whi*(ahi+alo), f32 accum; partials -> LDS (XOR-swizzled).
template <int MT>
__device__ __forceinline__ void cell_compute(
    const _Float16* __restrict__ a0h, const _Float16* __restrict__ a0l,
    const _Float16* __restrict__ a1h, const _Float16* __restrict__ a1l,
    const half8 (&wf)[2][32], float (*pw)[64], int ln, int lane) {
    f32x16 acc[MT][2];
#pragma unroll
    for (int mt = 0; mt < MT; ++mt)
#pragma unroll
        for (int nt = 0; nt < 2; ++nt)
#pragma unroll
            for (int r = 0; r < 16; ++r) acc[mt][nt][r] = 0.f;

#pragma unroll
    for (int ks = 0; ks < 32; ++ks) {
        half8 x0h = *reinterpret_cast<const half8*>(a0h + ks * 16);
        half8 x0l = *reinterpret_cast<const half8*>(a0l + ks * 16);
        if (MT == 2) {
            half8 x1h = *reinterpret_cast<const half8*>(a1h + ks * 16);
            half8 x1l = *reinterpret_cast<const half8*>(a1l + ks * 16);
            acc[0][0] = __builtin_amdgcn_mfma_f32_32x32x16_f16(x0h, wf[0][ks], acc[0][0], 0, 0, 0);
            acc[0][1] = __builtin_amdgcn_mfma_f32_32x32x16_f16(x0h, wf[1][ks], acc[0][1], 0, 0, 0);
            acc[1][0] = __builtin_amdgcn_mfma_f32_32x32x16_f16(x1h, wf[0][ks], acc[1][0], 0, 0, 0);
            acc[1][1] = __builtin_amdgcn_mfma_f32_32x32x16_f16(x1h, wf[1][ks], acc[1][1], 0, 0, 0);
            acc[0][0] = __builtin_amdgcn_mfma_f32_32x32x16_f16(x0l, wf[0][ks], acc[0][0], 0, 0, 0);
            acc[0][1] = __builtin_amdgcn_mfma_f32_32x32x16_f16(x0l, wf[1][ks], acc[0][1], 0, 0, 0);
            acc[1][0] = __builtin_amdgcn_mfma_f32_32x32x16_f16(x1l, wf[0][ks], acc[1][0], 0, 0, 0);
            acc[1][1] = __builtin_amdgcn_mfma_f32_32x32x16_f16(x1l, wf[1][ks], acc[1][1], 0, 0, 0);
        } else {
            acc[0][0] = __builtin_amdgcn_mfma_f32_32x32x16_f16(x0h, wf[0][ks], acc[0][0], 0, 0, 0);
            acc[0][1] = __builtin_amdgcn_mfma_f32_32x32x16_f16(x0h, wf[1][ks], acc[0][1], 0, 0, 0);
            acc[0][0] = __builtin_amdgcn_mfma_f32_32x32x16_f16(x0l, wf[0][ks], acc[0][0], 0, 0, 0);
            acc[0][1] = __builtin_amdgcn_mfma_f32_32x32x16_f16(x0l, wf[1][ks], acc[0][1], 0, 0, 0);
        }
    }
    // C layout (32x32): n = lane&31 (+32*nt), m = (r&3) + 8*(r>>2) + 4*(lane>>5) (+32*mt)
#pragma unroll
    for (int mt = 0; mt < MT; ++mt)
#pragma unroll
        for (int nt = 0; nt < 2; ++nt)
#pragma unroll
            for (int r = 0; r < 16; ++r) {
                int m = mt * 32 + 4 * (lane >> 5) + (r & 3) + 8 * (r >> 2);
                int n = nt * 32 + ln;
                pw[m][n ^ ((m & 7) << 2)] = acc[mt][nt][r];
            }
}

// Persistent wavefront LSTM: 256 blocks (1/CU), layer = blk>>6, 16 hidden units per blk.
// Weights fp16 in VGPRs (256/lane); h,c fp32 in thread registers across the sequence.
__global__ __launch_bounds__(256, 1) void lstm_persistent(
    const int* __restrict__ padded_in, const int* __restrict__ in_lengths,
    const float* __restrict__ w_ih, const float* __restrict__ w_hh,
    const float* __restrict__ biasf, int* __restrict__ bar,
    const _Float16* __restrict__ ehi, const _Float16* __restrict__ elo,
    _Float16* __restrict__ hbhi, _Float16* __restrict__ hblo,
    _Float16* __restrict__ ybhi, _Float16* __restrict__ yblo,
    float* __restrict__ out) {
    __shared__ __align__(16) float part[4][64][64];  // 64 KB wave partials

    const int cu = blockIdx.x;
    const int layer = cu >> 6;
    const int j0 = (cu & 63) * 16;
    const int tid = threadIdx.x;
    const int wave = tid >> 6;
    const int lane = tid & 63;
    const int ln = lane & 31;
    const int khalf = (lane >> 5) * 8;

    // ---- one-time weight preload: fp32 -> fp16 frags in registers (256 VGPR/lane)
    half8 wf[2][32];
    {
        const float* wsrc = (wave < 2) ? w_ih : w_hh;
        const int kb = (wave & 1) * 512;
#pragma unroll
        for (int nt = 0; nt < 2; ++nt) {
            int n = nt * 32 + ln;
            const float* rowp =
                wsrc + ((size_t)layer * 4 * Hn + (n >> 4) * Hn + j0 + (n & 15)) * Hn + kb + khalf;
#pragma unroll
            for (int ks = 0; ks < 32; ++ks) {
                f32x4 a = *reinterpret_cast<const f32x4*>(rowp + ks * 16);
                f32x4 b = *reinterpret_cast<const f32x4*>(rowp + ks * 16 + 4);
                half8 h;
                h[0] = (_Float16)a[0]; h[1] = (_Float16)a[1];
                h[2] = (_Float16)a[2]; h[3] = (_Float16)a[3];
                h[4] = (_Float16)b[0]; h[5] = (_Float16)b[1];
                h[6] = (_Float16)b[2]; h[7] = (_Float16)b[3];
                wf[nt][ks] = h;
            }
        }
    }

    // epilogue ownership: thread -> batch row brow, 4 units jcol..jcol+3
    const int brow = tid >> 2;
    const int jcol = (tid & 3) * 4;
    float bias[4][4];
#pragma unroll
    for (int g = 0; g < 4; ++g)
#pragma unroll
        for (int p = 0; p < 4; ++p)
            bias[g][p] = biasf[layer * 4096 + g * 1024 + j0 + jcol + p];

    float creg[4] = {0.f, 0.f, 0.f, 0.f};
    float hreg[4] = {0.f, 0.f, 0.f, 0.f};

    for (int w = 0; w < Sn + Ln - 1; ++w) {
        const int t = w - layer;
        if (t >= 0 && t < Sn) {
            const int bs = in_lengths[t];
            const int pin = t & 1;
            const int pout = pin ^ 1;

            // per-wave A-source pointers (hi/lo fp16 planes), K-slice = wave*512
            const _Float16 *a0h, *a0l, *a1h, *a1l;
            {
                const int m0 = ln, m1 = 32 + ln;
                if (wave < 2) {
                    const int kb = wave * 512 + khalf;
                    if (layer == 0) {
                        int i0 = padded_in[m0 * Sn + t];
                        int i1 = padded_in[m1 * Sn + t];
                        a0h = ehi + (size_t)i0 * Hn + kb;
                        a0l = elo + (size_t)i0 * Hn + kb;
                        a1h = ehi + (size_t)i1 * Hn + kb;
                        a1l = elo + (size_t)i1 * Hn + kb;
                    } else {
                        size_t base = (size_t)(pin * 3 + layer - 1) * Bn * Hn + kb;
                        a0h = ybhi + base + (size_t)m0 * Hn;
                        a0l = yblo + base + (size_t)m0 * Hn;
                        a1h = ybhi + base + (size_t)m1 * Hn;
                        a1l = yblo + base + (size_t)m1 * Hn;
                    }
                } else {
                    const int kb = (wave - 2) * 512 + khalf;
                    size_t base = (size_t)(pin * Ln + layer) * Bn * Hn + kb;
                    a0h = hbhi + base + (size_t)m0 * Hn;
                    a0l = hblo + base + (size_t)m0 * Hn;
                    a1h = hbhi + base + (size_t)m1 * Hn;
                    a1l = hblo + base + (size_t)m1 * Hn;
                }
            }

            if (bs > 32) cell_compute<2>(a0h, a0l, a1h, a1l, wf, part[wave], ln, lane);
            else         cell_compute<1>(a0h, a0l, a1h, a1l, wf, part[wave], ln, lane);

            __syncthreads();

            // cross-wave K-reduction + bias
            float gsum[4][4];
#pragma unroll
            for (int g = 0; g < 4; ++g) {
                int nidx = (g * 16 + jcol) ^ ((brow & 7) << 2);
                f32x4 s = *reinterpret_cast<const f32x4*>(&part[0][brow][nidx]);
#pragma unroll
                for (int wv = 1; wv < 4; ++wv)
                    s = s + *reinterpret_cast<const f32x4*>(&part[wv][brow][nidx]);
#pragma unroll
                for (int p = 0; p < 4; ++p) gsum[g][p] = s[p] + bias[g][p];
            }

            const bool active = (brow < bs);
            const int J = j0 + jcol;
            float hold[4], ysum[4];
#pragma unroll
            for (int p = 0; p < 4; ++p) {
                float cn = sigmf(gsum[1][p]) * creg[p] + sigmf(gsum[0][p]) * tanhf_(gsum[2][p]);
                float hn = sigmf(gsum[3][p]) * tanhf_(cn);
                hold[p] = hreg[p];
                if (active) { creg[p] = cn; hreg[p] = hn; }
                ysum[p] = hreg[p] + hold[p];  // active: h_new + h_old; inactive: unused
            }
            {   // h broadcast (hi/lo fp16, t-parity double buffer)
                half4v hh, hl;
#pragma unroll
                for (int p = 0; p < 4; ++p) {
                    _Float16 a = (_Float16)hreg[p];
                    hh[p] = a;
                    hl[p] = (_Float16)(hreg[p] - (float)a);
                }
                size_t ho = ((size_t)(pout * Ln + layer) * Bn + brow) * Hn + J;
                *reinterpret_cast<half4v*>(&hbhi[ho]) = hh;
                *reinterpret_cast<half4v*>(&hblo[ho]) = hl;
            }
            if (layer < 3) {  // y interface feed (same-parity slot, own interface index)
                half4v yh, yl;
                if (active) {
#pragma unroll
                    for (int p = 0; p < 4; ++p) {
                        _Float16 a = (_Float16)ysum[p];
                        yh[p] = a;
                        yl[p] = (_Float16)(ysum[p] - (float)a);
                    }
                } else {  // carry incoming y (x_t for l=0) verbatim
                    if (layer == 0) {
                        int ib = padded_in[brow * Sn + t];
                        yh = *reinterpret_cast<const half4v*>(&ehi[(size_t)ib * Hn + J]);
                        yl = *reinterpret_cast<const half4v*>(&elo[(size_t)ib * Hn + J]);
                    } else {
                        size_t yo = ((size_t)(pin * 3 + layer - 1) * Bn + brow) * Hn + J;
                        yh = *reinterpret_cast<const half4v*>(&ybhi[yo]);
                        yl = *reinterpret_cast<const half4v*>(&yblo[yo]);
                    }
                }
                size_t yo2 = ((size_t)(pin * 3 + layer) * Bn + brow) * Hn + J;
                *reinterpret_cast<half4v*>(&ybhi[yo2]) = yh;
                *reinterpret_cast<half4v*>(&yblo[yo2]) = yl;
            }
        }
        grid_barrier(bar, cu);
    }

    if (layer == 3) {
        f32x4 o;
#pragma unroll
        for (int p = 0; p < 4; ++p) o[p] = hreg[p];
        *reinterpret_cast<f32x4*>(&out[(size_t)brow * Hn + j0 + jcol]) = o;
    }
}

extern "C" void kernel_launch(void* const* d_in, const int* in_sizes, int n_in,
                              void* d_out, int out_size, void* d_ws, size_t ws_size,
                              hipStream_t stream) {
    const int* padded_in = (const int*)d_in[0];
    const int* in_lengths = (const int*)d_in[1];
    const float* emb = (const float*)d_in[2];
    const float* w_ih = (const float*)d_in[3];
    const float* w_hh = (const float*)d_in[4];
    const float* b_ih = (const float*)d_in[5];
    const float* b_hh = (const float*)d_in[6];
    float* outp = (float*)d_out;

    // workspace (~3.7 MB), all segments 16B-aligned
    char* w = (char*)d_ws;
    int* bar = (int*)w;                    w += BAR_INTS * 4;
    float* biasf = (float*)w;              w += (size_t)Ln * 4 * Hn * 4;
    _Float16* ehi = (_Float16*)w;          w += (size_t)Vn * Hn * 2;
    _Float16* elo = (_Float16*)w;          w += (size_t)Vn * Hn * 2;
    _Float16* hbhi = (_Float16*)w;         w += (size_t)2 * Ln * Bn * Hn * 2;
    _Float16* hblo = (_Float16*)w;         w += (size_t)2 * Ln * Bn * Hn * 2;
    _Float16* ybhi = (_Float16*)w;         w += (size_t)2 * 3 * Bn * Hn * 2;
    _Float16* yblo = (_Float16*)w;         w += (size_t)2 * 3 * Bn * Hn * 2;

    init_kernel<<<256, 256, 0, stream>>>(b_ih, b_hh, emb, bar, biasf, ehi, elo, hbhi, hblo);
    lstm_persistent<<<NBLK, 256, 0, stream>>>(padded_in, in_lengths, w_ih, w_hh, biasf, bar,
                                              ehi, elo, hbhi, hblo, ybhi, yblo, outp);
}

// Round 5
// 16532.201 us; speedup vs baseline: 6.6022x; 1.5062x over previous
//
#include <hip/hip_runtime.h>
#include <hip/hip_fp16.h>

// EncoderRNN: V=29, H=1024, L=4, B=64, S=512. Inputs/out are FLOAT32 (proven R1/R2).
#define Vn 29
#define Hn 1024
#define Ln 4
#define Bn 64
#define Sn 512
#define BH (Bn * Hn)
#define NBLK 256

typedef _Float16 half8 __attribute__((ext_vector_type(8)));
typedef _Float16 half4v __attribute__((ext_vector_type(4)));
typedef float f32x16 __attribute__((ext_vector_type(16)));
typedef float f32x4 __attribute__((ext_vector_type(4)));

__device__ __forceinline__ float sigmf(float x) { return 1.0f / (1.0f + __expf(-x)); }
__device__ __forceinline__ float tanhf_(float x) { return 1.0f - 2.0f / (__expf(2.0f * x) + 1.0f); }

// barrier block: c0[8] padded 32 ints apart (0..255), c1 at [256], gen at [288]
#define BAR_INTS 320

__global__ void init_kernel(const float* __restrict__ bi, const float* __restrict__ bh,
                            const float* __restrict__ emb, int* __restrict__ bar,
                            float* __restrict__ biasf,
                            _Float16* __restrict__ ehi, _Float16* __restrict__ elo,
                            _Float16* __restrict__ hbhi, _Float16* __restrict__ hblo) {
    int i = blockIdx.x * blockDim.x + threadIdx.x;
    int stride = gridDim.x * blockDim.x;
    for (int k = i; k < BAR_INTS; k += stride) bar[k] = 0;
    for (int k = i; k < Ln * 4 * Hn; k += stride) biasf[k] = bi[k] + bh[k];
    for (int k = i; k < Vn * Hn; k += stride) {
        float e = (k < Hn) ? 0.f : emb[k];  // padding_idx=0 row zero
        _Float16 h = (_Float16)e;
        ehi[k] = h;
        elo[k] = (_Float16)(e - (float)h);
    }
    for (int k = i; k < 2 * Ln * Bn * Hn; k += stride) {
        hbhi[k] = (_Float16)0.f;
        hblo[k] = (_Float16)0.f;
    }
}

// Grid barrier, minimal coherence traffic:
//   one RELEASE fence (wbl2) per block, RELAXED arrival RMWs, RELAXED spin,
//   one ACQUIRE fence (inv) per block after release observed.
// R4's acquire-per-poll invalidated the XCD L2 thousands of times per step.
__device__ __forceinline__ void grid_barrier(int* __restrict__ bar, int bid) {
    __syncthreads();
    if (threadIdx.x == 0) {
        __builtin_amdgcn_fence(__ATOMIC_RELEASE, "agent");
        int* c0 = bar + (bid & 7) * 32;
        int* c1 = bar + 256;
        int* gen = bar + 288;
        int my = __hip_atomic_load(gen, __ATOMIC_RELAXED, __HIP_MEMORY_SCOPE_AGENT);
        bool rel = false;
        int p = __hip_atomic_fetch_add(c0, 1, __ATOMIC_RELAXED, __HIP_MEMORY_SCOPE_AGENT);
        if (p == 31) {
            int q = __hip_atomic_fetch_add(c1, 1, __ATOMIC_RELAXED, __HIP_MEMORY_SCOPE_AGENT);
            if (q == 7) {  // reset-before-release; release store orders the resets
                for (int g = 0; g < 8; ++g)
                    __hip_atomic_store(bar + g * 32, 0, __ATOMIC_RELAXED, __HIP_MEMORY_SCOPE_AGENT);
                __hip_atomic_store(c1, 0, __ATOMIC_RELAXED, __HIP_MEMORY_SCOPE_AGENT);
                __hip_atomic_store(gen, my + 1, __ATOMIC_RELEASE, __HIP_MEMORY_SCOPE_AGENT);
                rel = true;
            }
        }
        if (!rel) {
            long long t0 = clock64();
            while (__hip_atomic_load(gen, __ATOMIC_RELAXED, __HIP_MEMORY_SCOPE_AGENT) == my) {
                __builtin_amdgcn_s_sleep(2);
                if (clock64() - t0 > 2000000000LL) break;  // ~0.85 s escape hatch
            }
        }
        __builtin_amdgcn_fence(__ATOMIC_ACQUIRE, "agent");
    }
    __syncthreads();
}

// MFMA for one cell, one wave: K-slice 256 (16 chunks), N=64 (2 tiles), MT batch tiles.
template <int MT>
__device__ __forceinline__ void cell_compute(
    const _Float16* __restrict__ a0h, const _Float16* __restrict__ a0l,
    const _Float16* __restrict__ a1h, const _Float16* __restrict__ a1l,
    const half8 (&wf)[2][16], f32x16 (&acc)[MT][2]) {
#pragma unroll
    for (int mt = 0; mt < MT; ++mt)
#pragma unroll
        for (int nt = 0; nt < 2; ++nt)
#pragma unroll
            for (int r = 0; r < 16; ++r) acc[mt][nt][r] = 0.f;

#pragma unroll
    for (int ks = 0; ks < 16; ++ks) {
        half8 x0h = *reinterpret_cast<const half8*>(a0h + ks * 16);
        half8 x0l = *reinterpret_cast<const half8*>(a0l + ks * 16);
        acc[0][0] = __builtin_amdgcn_mfma_f32_32x32x16_f16(x0h, wf[0][ks], acc[0][0], 0, 0, 0);
        acc[0][1] = __builtin_amdgcn_mfma_f32_32x32x16_f16(x0h, wf[1][ks], acc[0][1], 0, 0, 0);
        acc[0][0] = __builtin_amdgcn_mfma_f32_32x32x16_f16(x0l, wf[0][ks], acc[0][0], 0, 0, 0);
        acc[0][1] = __builtin_amdgcn_mfma_f32_32x32x16_f16(x0l, wf[1][ks], acc[0][1], 0, 0, 0);
        if (MT == 2) {
            half8 x1h = *reinterpret_cast<const half8*>(a1h + ks * 16);
            half8 x1l = *reinterpret_cast<const half8*>(a1l + ks * 16);
            acc[1][0] = __builtin_amdgcn_mfma_f32_32x32x16_f16(x1h, wf[0][ks], acc[1][0], 0, 0, 0);
            acc[1][1] = __builtin_amdgcn_mfma_f32_32x32x16_f16(x1h, wf[1][ks], acc[1][1], 0, 0, 0);
            acc[1][0] = __builtin_amdgcn_mfma_f32_32x32x16_f16(x1l, wf[0][ks], acc[1][0], 0, 0, 0);
            acc[1][1] = __builtin_amdgcn_mfma_f32_32x32x16_f16(x1l, wf[1][ks], acc[1][1], 0, 0, 0);
        }
    }
}

// part write helpers: C layout (32x32): n=lane&31, m=4*(lane>>5)+(r&3)+8*(r>>2)
template <int MT, bool ADD>
__device__ __forceinline__ void part_write(float (*pw)[64], const f32x16 (&acc)[MT][2],
                                           int lane) {
    const int ln = lane & 31;
#pragma unroll
    for (int mt = 0; mt < MT; ++mt)
#pragma unroll
        for (int nt = 0; nt < 2; ++nt)
#pragma unroll
            for (int r = 0; r < 16; ++r) {
                int m = mt * 32 + 4 * (lane >> 5) + (r & 3) + 8 * (r >> 2);
                int n = nt * 32 + ln;
                int idx = n ^ ((m & 7) << 2);
                if (ADD) pw[m][idx] += acc[mt][nt][r];
                else pw[m][idx] = acc[mt][nt][r];
            }
}

// Persistent wavefront LSTM: 256 blocks x 512 threads (8 waves, 2/SIMD).
// Wave w: K-slice 256 (w<4: y/w_ih, w>=4: h/w_hh), full N=64.
// wf = 128 VGPR/lane (no spill); h,c fp32 in regs of threads 0..255.
__global__ __launch_bounds__(512, 1) void lstm_persistent(
    const int* __restrict__ padded_in, const int* __restrict__ in_lengths,
    const float* __restrict__ w_ih, const float* __restrict__ w_hh,
    const float* __restrict__ biasf, int* __restrict__ bar,
    const _Float16* __restrict__ ehi, const _Float16* __restrict__ elo,
    _Float16* __restrict__ hbhi, _Float16* __restrict__ hblo,
    _Float16* __restrict__ ybhi, _Float16* __restrict__ yblo,
    float* __restrict__ out) {
    __shared__ __align__(16) float part[4][64][64];  // 64 KB

    const int cu = blockIdx.x;
    const int layer = cu >> 6;
    const int j0 = (cu & 63) * 16;
    const int tid = threadIdx.x;
    const int wv = tid >> 6;
    const int lane = tid & 63;
    const int ln = lane & 31;
    const int khalf = (lane >> 5) * 8;
    const bool isH = (wv >= 4);
    const int kb = (isH ? (wv - 4) : wv) * 256;

    // ---- one-time weight preload: fp32 -> fp16 frags, 128 VGPR/lane
    half8 wf[2][16];
    {
        const float* wsrc = isH ? w_hh : w_ih;
#pragma unroll
        for (int nt = 0; nt < 2; ++nt) {
            int n = nt * 32 + ln;
            const float* rowp =
                wsrc + ((size_t)layer * 4 * Hn + (n >> 4) * Hn + j0 + (n & 15)) * Hn + kb + khalf;
#pragma unroll
            for (int ks = 0; ks < 16; ++ks) {
                f32x4 a = *reinterpret_cast<const f32x4*>(rowp + ks * 16);
                f32x4 b = *reinterpret_cast<const f32x4*>(rowp + ks * 16 + 4);
                half8 h;
                h[0] = (_Float16)a[0]; h[1] = (_Float16)a[1];
                h[2] = (_Float16)a[2]; h[3] = (_Float16)a[3];
                h[4] = (_Float16)b[0]; h[5] = (_Float16)b[1];
                h[6] = (_Float16)b[2]; h[7] = (_Float16)b[3];
                wf[nt][ks] = h;
            }
        }
    }

    // epilogue ownership (threads 0..255): batch row brow, 4 units jcol..jcol+3
    const int brow = (tid & 255) >> 2;
    const int jcol = (tid & 3) * 4;
    float bias[4][4];
#pragma unroll
    for (int g = 0; g < 4; ++g)
#pragma unroll
        for (int p = 0; p < 4; ++p)
            bias[g][p] = biasf[layer * 4096 + g * 1024 + j0 + jcol + p];

    float creg[4] = {0.f, 0.f, 0.f, 0.f};
    float hreg[4] = {0.f, 0.f, 0.f, 0.f};

    for (int w = 0; w < Sn + Ln - 1; ++w) {
        const int t = w - layer;
        if (t >= 0 && t < Sn) {
            const int bs = in_lengths[t];
            const int pin = t & 1;
            const int pout = pin ^ 1;

            // per-wave A-source pointers (hi/lo fp16 planes) for its K-slice
            const _Float16 *a0h, *a0l, *a1h, *a1l;
            if (!isH) {
                const int ko = kb + khalf;
                if (layer == 0) {
                    int i0 = padded_in[ln * Sn + t];
                    int i1 = padded_in[(32 + ln) * Sn + t];
                    a0h = ehi + (size_t)i0 * Hn + ko;
                    a0l = elo + (size_t)i0 * Hn + ko;
                    a1h = ehi + (size_t)i1 * Hn + ko;
                    a1l = elo + (size_t)i1 * Hn + ko;
                } else {
                    size_t base = (size_t)(pin * 3 + layer - 1) * BH + ko;
                    a0h = ybhi + base + (size_t)ln * Hn;
                    a0l = yblo + base + (size_t)ln * Hn;
                    a1h = ybhi + base + (size_t)(32 + ln) * Hn;
                    a1l = yblo + base + (size_t)(32 + ln) * Hn;
                }
            } else {
                size_t base = (size_t)(pin * Ln + layer) * BH + kb + khalf;
                a0h = hbhi + base + (size_t)ln * Hn;
                a0l = hblo + base + (size_t)ln * Hn;
                a1h = hbhi + base + (size_t)(32 + ln) * Hn;
                a1l = hblo + base + (size_t)(32 + ln) * Hn;
            }

            // compute; two-phase partial accumulation (waves 0-3 store, 4-7 add)
            if (bs > 32) {
                f32x16 acc[2][2];
                cell_compute<2>(a0h, a0l, a1h, a1l, wf, acc);
                if (wv < 4) part_write<2, false>(part[wv], acc, lane);
                __syncthreads();
                if (wv >= 4) part_write<2, true>(part[wv - 4], acc, lane);
            } else {
                f32x16 acc[1][2];
                cell_compute<1>(a0h, a0l, a1h, a1l, wf, acc);
                if (wv < 4) part_write<1, false>(part[wv], acc, lane);
                __syncthreads();
                if (wv >= 4) part_write<1, true>(part[wv - 4], acc, lane);
            }
            __syncthreads();

            if (tid < 256) {
                // cross-wave K-reduction + bias
                float gsum[4][4];
#pragma unroll
                for (int g = 0; g < 4; ++g) {
                    int nidx = (g * 16 + jcol) ^ ((brow & 7) << 2);
                    f32x4 s = *reinterpret_cast<const f32x4*>(&part[0][brow][nidx]);
#pragma unroll
                    for (int p2 = 1; p2 < 4; ++p2)
                        s = s + *reinterpret_cast<const f32x4*>(&part[p2][brow][nidx]);
#pragma unroll
                    for (int p = 0; p < 4; ++p) gsum[g][p] = s[p] + bias[g][p];
                }

                const bool active = (brow < bs);
                const int J = j0 + jcol;
                float hold[4], ysum[4];
#pragma unroll
                for (int p = 0; p < 4; ++p) {
                    float cn = sigmf(gsum[1][p]) * creg[p] + sigmf(gsum[0][p]) * tanhf_(gsum[2][p]);
                    float hn = sigmf(gsum[3][p]) * tanhf_(cn);
                    hold[p] = hreg[p];
                    if (active) { creg[p] = cn; hreg[p] = hn; }
                    ysum[p] = hreg[p] + hold[p];
                }
                {   // h broadcast (hi/lo fp16, t-parity double buffer)
                    half4v hh, hl;
#pragma unroll
                    for (int p = 0; p < 4; ++p) {
                        _Float16 a = (_Float16)hreg[p];
                        hh[p] = a;
                        hl[p] = (_Float16)(hreg[p] - (float)a);
                    }
                    size_t ho = ((size_t)(pout * Ln + layer) * Bn + brow) * Hn + J;
                    *reinterpret_cast<half4v*>(&hbhi[ho]) = hh;
                    *reinterpret_cast<half4v*>(&hblo[ho]) = hl;
                }
                if (layer < 3) {  // y interface feed (same-parity slot)
                    half4v yh, yl;
                    if (active) {
#pragma unroll
                        for (int p = 0; p < 4; ++p) {
                            _Float16 a = (_Float16)ysum[p];
                            yh[p] = a;
                            yl[p] = (_Float16)(ysum[p] - (float)a);
                        }
                    } else {  // carry incoming y (x_t for l=0) verbatim
                        if (layer == 0) {
                            int ib = padded_in[brow * Sn + t];
                            yh = *reinterpret_cast<const half4v*>(&ehi[(size_t)ib * Hn + J]);
                            yl = *reinterpret_cast<const half4v*>(&elo[(size_t)ib * Hn + J]);
                        } else {
                            size_t yo = ((size_t)(pin * 3 + layer - 1) * Bn + brow) * Hn + J;
                            yh = *reinterpret_cast<const half4v*>(&ybhi[yo]);
                            yl = *reinterpret_cast<const half4v*>(&yblo[yo]);
                        }
                    }
                    size_t yo2 = ((size_t)(pin * 3 + layer) * Bn + brow) * Hn + J;
                    *reinterpret_cast<half4v*>(&ybhi[yo2]) = yh;
                    *reinterpret_cast<half4v*>(&yblo[yo2]) = yl;
                }
            }
        }
        grid_barrier(bar, cu);
    }

    if (layer == 3 && tid < 256) {
        f32x4 o;
#pragma unroll
        for (int p = 0; p < 4; ++p) o[p] = hreg[p];
        *reinterpret_cast<f32x4*>(&out[(size_t)brow * Hn + j0 + jcol]) = o;
    }
}

extern "C" void kernel_launch(void* const* d_in, const int* in_sizes, int n_in,
                              void* d_out, int out_size, void* d_ws, size_t ws_size,
                              hipStream_t stream) {
    const int* padded_in = (const int*)d_in[0];
    const int* in_lengths = (const int*)d_in[1];
    const float* emb = (const float*)d_in[2];
    const float* w_ih = (const float*)d_in[3];
    const float* w_hh = (const float*)d_in[4];
    const float* b_ih = (const float*)d_in[5];
    const float* b_hh = (const float*)d_in[6];
    float* outp = (float*)d_out;

    // workspace (~3.7 MB), all segments 16B-aligned
    char* w = (char*)d_ws;
    int* bar = (int*)w;                    w += BAR_INTS * 4;
    float* biasf = (float*)w;              w += (size_t)Ln * 4 * Hn * 4;
    _Float16* ehi = (_Float16*)w;          w += (size_t)Vn * Hn * 2;
    _Float16* elo = (_Float16*)w;          w += (size_t)Vn * Hn * 2;
    _Float16* hbhi = (_Float16*)w;         w += (size_t)2 * Ln * Bn * Hn * 2;
    _Float16* hblo = (_Float16*)w;         w += (size_t)2 * Ln * Bn * Hn * 2;
    _Float16* ybhi = (_Float16*)w;         w += (size_t)2 * 3 * Bn * Hn * 2;
    _Float16* yblo = (_Float16*)w;         w += (size_t)2 * 3 * Bn * Hn * 2;

    init_kernel<<<256, 256, 0, stream>>>(b_ih, b_hh, emb, bar, biasf, ehi, elo, hbhi, hblo);
    lstm_persistent<<<NBLK, 512, 0, stream>>>(padded_in, in_lengths, w_ih, w_hh, biasf, bar,
                                              ehi, elo, hbhi, hblo, ybhi, yblo, outp);
}

// Round 6
// 9701.779 us; speedup vs baseline: 11.2504x; 1.7040x over previous
//
#include <hip/hip_runtime.h>
#include <hip/hip_fp16.h>

// EncoderRNN: V=29, H=1024, L=4, B=64, S=512. Inputs/out are FLOAT32 (proven R1/R2).
#define Vn 29
#define Hn 1024
#define Ln 4
#define Bn 64
#define Sn 512
#define BH (Bn * Hn)
#define NBLK 256

typedef _Float16 half8 __attribute__((ext_vector_type(8)));
typedef _Float16 half4v __attribute__((ext_vector_type(4)));
typedef float f32x16 __attribute__((ext_vector_type(16)));
typedef float f32x4 __attribute__((ext_vector_type(4)));

__device__ __forceinline__ float sigmf(float x) { return 1.0f / (1.0f + __expf(-x)); }
__device__ __forceinline__ float tanhf_(float x) { return 1.0f - 2.0f / (__expf(2.0f * x) + 1.0f); }

// --- device-coherent (LLC) access helpers: relaxed agent-scope atomics.
// These compile to flagged global loads/stores (no L2 dirty state, no fences).
__device__ __forceinline__ half8 ldg_coh8(const _Float16* p) {
    const unsigned long long* q = (const unsigned long long*)p;
    union { unsigned long long u[2]; half8 h; } c;
    c.u[0] = __hip_atomic_load(q, __ATOMIC_RELAXED, __HIP_MEMORY_SCOPE_AGENT);
    c.u[1] = __hip_atomic_load(q + 1, __ATOMIC_RELAXED, __HIP_MEMORY_SCOPE_AGENT);
    return c.h;
}
__device__ __forceinline__ half4v ldg_coh4(const _Float16* p) {
    union { unsigned long long u; half4v h; } c;
    c.u = __hip_atomic_load((const unsigned long long*)p, __ATOMIC_RELAXED,
                            __HIP_MEMORY_SCOPE_AGENT);
    return c.h;
}
__device__ __forceinline__ void stg_coh4(_Float16* p, half4v v) {
    union { half4v h; unsigned long long u; } c;
    c.h = v;
    __hip_atomic_store((unsigned long long*)p, c.u, __ATOMIC_RELAXED,
                       __HIP_MEMORY_SCOPE_AGENT);
}

// barrier block: c0[8] padded 32 ints apart (0..255), c1 at [256], gen at [288]
#define BAR_INTS 320

__global__ void init_kernel(const float* __restrict__ bi, const float* __restrict__ bh,
                            const float* __restrict__ emb, int* __restrict__ bar,
                            float* __restrict__ biasf, _Float16* __restrict__ ehi,
                            _Float16* __restrict__ hbh) {
    int i = blockIdx.x * blockDim.x + threadIdx.x;
    int stride = gridDim.x * blockDim.x;
    for (int k = i; k < BAR_INTS; k += stride) bar[k] = 0;
    for (int k = i; k < Ln * 4 * Hn; k += stride) biasf[k] = bi[k] + bh[k];
    for (int k = i; k < Vn * Hn; k += stride)
        ehi[k] = (_Float16)((k < Hn) ? 0.f : emb[k]);  // padding_idx=0 row zero
    for (int k = i; k < 2 * Ln * Bn * Hn; k += stride) hbh[k] = (_Float16)0.f;
}

// Grid barrier with ZERO cache-maintenance ops: relaxed atomics only.
// All cross-block data moves via sc1 (agent-scope) accesses, so no wbl2/inv
// is needed — R4/R5's fences (32 wbl2+inv per XCD per step) were the cost.
// s_waitcnt vmcnt(0) orders this block's coherent stores before its arrival.
__device__ __forceinline__ void grid_barrier(int* __restrict__ bar, int bid) {
    asm volatile("s_waitcnt vmcnt(0)" ::: "memory");  // drain each wave's stores
    __syncthreads();
    if (threadIdx.x == 0) {
        int* c0 = bar + (bid & 7) * 32;
        int* c1 = bar + 256;
        int* gen = bar + 288;
        int my = __hip_atomic_load(gen, __ATOMIC_RELAXED, __HIP_MEMORY_SCOPE_AGENT);
        bool rel = false;
        int p = __hip_atomic_fetch_add(c0, 1, __ATOMIC_RELAXED, __HIP_MEMORY_SCOPE_AGENT);
        if (p == 31) {
            int q = __hip_atomic_fetch_add(c1, 1, __ATOMIC_RELAXED, __HIP_MEMORY_SCOPE_AGENT);
            if (q == 7) {  // reset-before-release; vmcnt drain orders resets < gen
                for (int g = 0; g < 8; ++g)
                    __hip_atomic_store(bar + g * 32, 0, __ATOMIC_RELAXED,
                                       __HIP_MEMORY_SCOPE_AGENT);
                __hip_atomic_store(c1, 0, __ATOMIC_RELAXED, __HIP_MEMORY_SCOPE_AGENT);
                asm volatile("s_waitcnt vmcnt(0)" ::: "memory");
                __hip_atomic_store(gen, my + 1, __ATOMIC_RELAXED, __HIP_MEMORY_SCOPE_AGENT);
                rel = true;
            }
        }
        if (!rel) {
            long long t0 = clock64();
            while (__hip_atomic_load(gen, __ATOMIC_RELAXED, __HIP_MEMORY_SCOPE_AGENT) == my) {
                __builtin_amdgcn_s_sleep(2);
                if (clock64() - t0 > 2000000000LL) break;  // ~0.85 s escape hatch
            }
        }
    }
    __syncthreads();
}

// MFMA for one cell, one wave: K-slice 256 (16 chunks), N=64 (2 tiles), MT batch tiles.
// Single fp16 A plane (error budget: fp16-W dominates), COH selects LLC vs cached loads.
template <int MT, bool COH>
__device__ __forceinline__ void cell_compute(
    const _Float16* __restrict__ a0, const _Float16* __restrict__ a1,
    const half8 (&wf)[2][16], f32x16 (&acc)[MT][2]) {
#pragma unroll
    for (int mt = 0; mt < MT; ++mt)
#pragma unroll
        for (int nt = 0; nt < 2; ++nt)
#pragma unroll
            for (int r = 0; r < 16; ++r) acc[mt][nt][r] = 0.f;

#pragma unroll
    for (int ks = 0; ks < 16; ++ks) {
        half8 x0 = COH ? ldg_coh8(a0 + ks * 16)
                       : *reinterpret_cast<const half8*>(a0 + ks * 16);
        acc[0][0] = __builtin_amdgcn_mfma_f32_32x32x16_f16(x0, wf[0][ks], acc[0][0], 0, 0, 0);
        acc[0][1] = __builtin_amdgcn_mfma_f32_32x32x16_f16(x0, wf[1][ks], acc[0][1], 0, 0, 0);
        if (MT == 2) {
            half8 x1 = COH ? ldg_coh8(a1 + ks * 16)
                           : *reinterpret_cast<const half8*>(a1 + ks * 16);
            acc[1][0] = __builtin_amdgcn_mfma_f32_32x32x16_f16(x1, wf[0][ks], acc[1][0], 0, 0, 0);
            acc[1][1] = __builtin_amdgcn_mfma_f32_32x32x16_f16(x1, wf[1][ks], acc[1][1], 0, 0, 0);
        }
    }
}

// part write: C layout (32x32): n=lane&31, m=4*(lane>>5)+(r&3)+8*(r>>2)
template <int MT, bool ADD>
__device__ __forceinline__ void part_write(float (*pw)[64], const f32x16 (&acc)[MT][2],
                                           int lane) {
    const int ln = lane & 31;
#pragma unroll
    for (int mt = 0; mt < MT; ++mt)
#pragma unroll
        for (int nt = 0; nt < 2; ++nt)
#pragma unroll
            for (int r = 0; r < 16; ++r) {
                int m = mt * 32 + 4 * (lane >> 5) + (r & 3) + 8 * (r >> 2);
                int n = nt * 32 + ln;
                int idx = n ^ ((m & 7) << 2);
                if (ADD) pw[m][idx] += acc[mt][nt][r];
                else pw[m][idx] = acc[mt][nt][r];
            }
}

// Persistent wavefront LSTM: 256 blocks x 512 threads (8 waves, 2/SIMD).
// Wave w: K-slice 256 (w<4: y/w_ih, w>=4: h/w_hh), full N=64.
// wf = 128 VGPR/lane; h,c fp32 in regs of threads 0..255; cross-block h/y via LLC.
__global__ __launch_bounds__(512, 1) void lstm_persistent(
    const int* __restrict__ padded_in, const int* __restrict__ in_lengths,
    const float* __restrict__ w_ih, const float* __restrict__ w_hh,
    const float* __restrict__ biasf, int* __restrict__ bar,
    const _Float16* __restrict__ ehi, _Float16* __restrict__ hbh,
    _Float16* __restrict__ ybh, float* __restrict__ out) {
    __shared__ __align__(16) float part[4][64][64];  // 64 KB

    const int cu = blockIdx.x;
    const int layer = cu >> 6;
    const int j0 = (cu & 63) * 16;
    const int tid = threadIdx.x;
    const int wv = tid >> 6;
    const int lane = tid & 63;
    const int ln = lane & 31;
    const int khalf = (lane >> 5) * 8;
    const bool isH = (wv >= 4);
    const int kb = (isH ? (wv - 4) : wv) * 256;

    // ---- one-time weight preload: fp32 -> fp16 frags, 128 VGPR/lane
    half8 wf[2][16];
    {
        const float* wsrc = isH ? w_hh : w_ih;
#pragma unroll
        for (int nt = 0; nt < 2; ++nt) {
            int n = nt * 32 + ln;
            const float* rowp =
                wsrc + ((size_t)layer * 4 * Hn + (n >> 4) * Hn + j0 + (n & 15)) * Hn + kb + khalf;
#pragma unroll
            for (int ks = 0; ks < 16; ++ks) {
                f32x4 a = *reinterpret_cast<const f32x4*>(rowp + ks * 16);
                f32x4 b = *reinterpret_cast<const f32x4*>(rowp + ks * 16 + 4);
                half8 h;
                h[0] = (_Float16)a[0]; h[1] = (_Float16)a[1];
                h[2] = (_Float16)a[2]; h[3] = (_Float16)a[3];
                h[4] = (_Float16)b[0]; h[5] = (_Float16)b[1];
                h[6] = (_Float16)b[2]; h[7] = (_Float16)b[3];
                wf[nt][ks] = h;
            }
        }
    }

    // epilogue ownership (threads 0..255): batch row brow, 4 units jcol..jcol+3
    const int brow = (tid & 255) >> 2;
    const int jcol = (tid & 3) * 4;
    float bias[4][4];
#pragma unroll
    for (int g = 0; g < 4; ++g)
#pragma unroll
        for (int p = 0; p < 4; ++p)
            bias[g][p] = biasf[layer * 4096 + g * 1024 + j0 + jcol + p];

    float creg[4] = {0.f, 0.f, 0.f, 0.f};
    float hreg[4] = {0.f, 0.f, 0.f, 0.f};

    for (int w = 0; w < Sn + Ln - 1; ++w) {
        const int t = w - layer;
        if (t >= 0 && t < Sn) {
            const int bs = in_lengths[t];
            const int pin = t & 1;
            const int pout = pin ^ 1;

            // per-wave A-source pointers for its K-slice
            const _Float16 *a0, *a1;
            bool coh;
            if (!isH) {
                const int ko = kb + khalf;
                if (layer == 0) {  // embedding: read-only, cacheable
                    a0 = ehi + (size_t)padded_in[ln * Sn + t] * Hn + ko;
                    a1 = ehi + (size_t)padded_in[(32 + ln) * Sn + t] * Hn + ko;
                    coh = false;
                } else {
                    size_t base = (size_t)(pin * 3 + layer - 1) * BH + ko;
                    a0 = ybh + base + (size_t)ln * Hn;
                    a1 = ybh + base + (size_t)(32 + ln) * Hn;
                    coh = true;
                }
            } else {
                size_t base = (size_t)(pin * Ln + layer) * BH + kb + khalf;
                a0 = hbh + base + (size_t)ln * Hn;
                a1 = hbh + base + (size_t)(32 + ln) * Hn;
                coh = true;
            }

            // compute; two-phase partial accumulation (waves 0-3 store, 4-7 add)
            if (bs > 32) {
                f32x16 acc[2][2];
                if (coh) cell_compute<2, true>(a0, a1, wf, acc);
                else cell_compute<2, false>(a0, a1, wf, acc);
                if (wv < 4) part_write<2, false>(part[wv], acc, lane);
                __syncthreads();
                if (wv >= 4) part_write<2, true>(part[wv - 4], acc, lane);
            } else {
                f32x16 acc[1][2];
                if (coh) cell_compute<1, true>(a0, a1, wf, acc);
                else cell_compute<1, false>(a0, a1, wf, acc);
                if (wv < 4) part_write<1, false>(part[wv], acc, lane);
                __syncthreads();
                if (wv >= 4) part_write<1, true>(part[wv - 4], acc, lane);
            }
            __syncthreads();

            if (tid < 256) {
                // cross-wave K-reduction + bias
                float gsum[4][4];
#pragma unroll
                for (int g = 0; g < 4; ++g) {
                    int nidx = (g * 16 + jcol) ^ ((brow & 7) << 2);
                    f32x4 s = *reinterpret_cast<const f32x4*>(&part[0][brow][nidx]);
#pragma unroll
                    for (int p2 = 1; p2 < 4; ++p2)
                        s = s + *reinterpret_cast<const f32x4*>(&part[p2][brow][nidx]);
#pragma unroll
                    for (int p = 0; p < 4; ++p) gsum[g][p] = s[p] + bias[g][p];
                }

                const bool active = (brow < bs);
                const int J = j0 + jcol;
                float hold[4], ysum[4];
#pragma unroll
                for (int p = 0; p < 4; ++p) {
                    float cn = sigmf(gsum[1][p]) * creg[p] + sigmf(gsum[0][p]) * tanhf_(gsum[2][p]);
                    float hn = sigmf(gsum[3][p]) * tanhf_(cn);
                    hold[p] = hreg[p];
                    if (active) { creg[p] = cn; hreg[p] = hn; }
                    ysum[p] = hreg[p] + hold[p];
                }
                {   // h broadcast (fp16, t-parity double buffer) -> LLC
                    half4v hh;
#pragma unroll
                    for (int p = 0; p < 4; ++p) hh[p] = (_Float16)hreg[p];
                    stg_coh4(&hbh[((size_t)(pout * Ln + layer) * Bn + brow) * Hn + J], hh);
                }
                if (layer < 3) {  // y interface feed (same-parity slot) -> LLC
                    half4v yh;
                    if (active) {
#pragma unroll
                        for (int p = 0; p < 4; ++p) yh[p] = (_Float16)ysum[p];
                    } else {  // carry incoming y (x_t for l=0) verbatim
                        if (layer == 0) {
                            int ib = padded_in[brow * Sn + t];
                            yh = *reinterpret_cast<const half4v*>(&ehi[(size_t)ib * Hn + J]);
                        } else {
                            yh = ldg_coh4(&ybh[((size_t)(pin * 3 + layer - 1) * Bn + brow) * Hn + J]);
                        }
                    }
                    stg_coh4(&ybh[((size_t)(pin * 3 + layer) * Bn + brow) * Hn + J], yh);
                }
            }
        }
        grid_barrier(bar, cu);
    }

    if (layer == 3 && tid < 256) {
        f32x4 o;
#pragma unroll
        for (int p = 0; p < 4; ++p) o[p] = hreg[p];
        *reinterpret_cast<f32x4*>(&out[(size_t)brow * Hn + j0 + jcol]) = o;
    }
}

extern "C" void kernel_launch(void* const* d_in, const int* in_sizes, int n_in,
                              void* d_out, int out_size, void* d_ws, size_t ws_size,
                              hipStream_t stream) {
    const int* padded_in = (const int*)d_in[0];
    const int* in_lengths = (const int*)d_in[1];
    const float* emb = (const float*)d_in[2];
    const float* w_ih = (const float*)d_in[3];
    const float* w_hh = (const float*)d_in[4];
    const float* b_ih = (const float*)d_in[5];
    const float* b_hh = (const float*)d_in[6];
    float* outp = (float*)d_out;

    // workspace (~2 MB), all segments 16B-aligned
    char* w = (char*)d_ws;
    int* bar = (int*)w;            w += BAR_INTS * 4;
    float* biasf = (float*)w;      w += (size_t)Ln * 4 * Hn * 4;
    _Float16* ehi = (_Float16*)w;  w += (size_t)Vn * Hn * 2;
    _Float16* hbh = (_Float16*)w;  w += (size_t)2 * Ln * Bn * Hn * 2;
    _Float16* ybh = (_Float16*)w;  w += (size_t)2 * 3 * Bn * Hn * 2;

    init_kernel<<<256, 256, 0, stream>>>(b_ih, b_hh, emb, bar, biasf, ehi, hbh);
    lstm_persistent<<<NBLK, 512, 0, stream>>>(padded_in, in_lengths, w_ih, w_hh, biasf, bar,
                                              ehi, hbh, ybh, outp);
}

// Round 7
// 7857.751 us; speedup vs baseline: 13.8906x; 1.2347x over previous
//
#include <hip/hip_runtime.h>
#include <hip/hip_fp16.h>

// EncoderRNN: V=29, H=1024, L=4, B=64, S=512. Inputs/out are FLOAT32 (proven R1/R2).
#define Vn 29
#define Hn 1024
#define Ln 4
#define Bn 64
#define Sn 512
#define BH (Bn * Hn)
#define NBLK 256

typedef _Float16 half8 __attribute__((ext_vector_type(8)));
typedef _Float16 half4v __attribute__((ext_vector_type(4)));
typedef float f32x16 __attribute__((ext_vector_type(16)));
typedef float f32x4 __attribute__((ext_vector_type(4)));

__device__ __forceinline__ float sigmf(float x) { return 1.0f / (1.0f + __expf(-x)); }
__device__ __forceinline__ float tanhf_(float x) { return 1.0f - 2.0f / (__expf(2.0f * x) + 1.0f); }

// --- LLC-coherent 16B load (bypass L1+L2, device coherence point), schedulable
// as a plain VMEM op; waitcnt discipline is OURS (see vwait*).
__device__ __forceinline__ half8 ldg_llc(const _Float16* p) {
    half8 v;
    asm volatile("global_load_dwordx4 %0, %1, off sc0 sc1" : "=v"(v) : "v"(p) : "memory");
    return v;
}
// Wait until <=CNT vector-mem ops outstanding; ties operands so dependent MFMAs
// cannot be scheduled above the wait. Extra earlier VMEM ops only make this
// conservative (vmcnt retires in issue order).
template <int CNT>
__device__ __forceinline__ void vwait1(half8& a) {
    asm volatile("s_waitcnt vmcnt(%1)" : "+v"(a) : "i"(CNT));
}
template <int CNT>
__device__ __forceinline__ void vwait2(half8& a, half8& b) {
    asm volatile("s_waitcnt vmcnt(%2)" : "+v"(a), "+v"(b) : "i"(CNT));
}

__device__ __forceinline__ half4v ldg_coh4(const _Float16* p) {
    union { unsigned long long u; half4v h; } c;
    c.u = __hip_atomic_load((const unsigned long long*)p, __ATOMIC_RELAXED,
                            __HIP_MEMORY_SCOPE_AGENT);
    return c.h;
}
__device__ __forceinline__ void stg_coh4(_Float16* p, half4v v) {
    union { half4v h; unsigned long long u; } c;
    c.h = v;
    __hip_atomic_store((unsigned long long*)p, c.u, __ATOMIC_RELAXED,
                       __HIP_MEMORY_SCOPE_AGENT);
}

// barrier block: c0[8] padded 32 ints apart (0..255), c1 at [256], gen at [288]
#define BAR_INTS 320

__global__ void init_kernel(const float* __restrict__ bi, const float* __restrict__ bh,
                            const float* __restrict__ emb, int* __restrict__ bar,
                            float* __restrict__ biasf, _Float16* __restrict__ ehi,
                            _Float16* __restrict__ hbh) {
    int i = blockIdx.x * blockDim.x + threadIdx.x;
    int stride = gridDim.x * blockDim.x;
    for (int k = i; k < BAR_INTS; k += stride) bar[k] = 0;
    for (int k = i; k < Ln * 4 * Hn; k += stride) biasf[k] = bi[k] + bh[k];
    for (int k = i; k < Vn * Hn; k += stride)
        ehi[k] = (_Float16)((k < Hn) ? 0.f : emb[k]);  // padding_idx=0 row zero
    for (int k = i; k < 2 * Ln * Bn * Hn; k += stride) hbh[k] = (_Float16)0.f;
}

// Grid barrier, zero cache-maintenance: relaxed agent atomics only (R6-proven).
__device__ __forceinline__ void grid_barrier(int* __restrict__ bar, int bid) {
    asm volatile("s_waitcnt vmcnt(0)" ::: "memory");  // drain this wave's stores
    __syncthreads();
    if (threadIdx.x == 0) {
        int* c0 = bar + (bid & 7) * 32;
        int* c1 = bar + 256;
        int* gen = bar + 288;
        int my = __hip_atomic_load(gen, __ATOMIC_RELAXED, __HIP_MEMORY_SCOPE_AGENT);
        bool rel = false;
        int p = __hip_atomic_fetch_add(c0, 1, __ATOMIC_RELAXED, __HIP_MEMORY_SCOPE_AGENT);
        if (p == 31) {
            int q = __hip_atomic_fetch_add(c1, 1, __ATOMIC_RELAXED, __HIP_MEMORY_SCOPE_AGENT);
            if (q == 7) {  // reset-before-release; vmcnt drain orders resets < gen
                for (int g = 0; g < 8; ++g)
                    __hip_atomic_store(bar + g * 32, 0, __ATOMIC_RELAXED,
                                       __HIP_MEMORY_SCOPE_AGENT);
                __hip_atomic_store(c1, 0, __ATOMIC_RELAXED, __HIP_MEMORY_SCOPE_AGENT);
                asm volatile("s_waitcnt vmcnt(0)" ::: "memory");
                __hip_atomic_store(gen, my + 1, __ATOMIC_RELAXED, __HIP_MEMORY_SCOPE_AGENT);
                rel = true;
            }
        }
        if (!rel) {
            long long t0 = clock64();
            int it = 0;
            while (__hip_atomic_load(gen, __ATOMIC_RELAXED, __HIP_MEMORY_SCOPE_AGENT) == my) {
                __builtin_amdgcn_s_sleep(1);
                if (((++it) & 255) == 0 && clock64() - t0 > 2000000000LL) break;  // escape
            }
        }
    }
    __syncthreads();
}

// ---- software-pipelined coherent K-loop: window of 4 chunk-pairs in flight.
template <int KS, int MT>
struct KStep {
    static __device__ __forceinline__ void run(const _Float16* a0, const _Float16* a1,
                                               half8 (&b0)[4], half8 (&b1)[4],
                                               const half8 (&wf)[2][16],
                                               f32x16 (&acc)[MT][2]) {
        constexpr int slot = KS & 3;
        constexpr int CNT = MT * ((KS + 4 < 16) ? 3 : (15 - KS));
        if constexpr (MT == 2) vwait2<CNT>(b0[slot], b1[slot]);
        else vwait1<CNT>(b0[slot]);
        acc[0][0] = __builtin_amdgcn_mfma_f32_32x32x16_f16(b0[slot], wf[0][KS], acc[0][0], 0, 0, 0);
        acc[0][1] = __builtin_amdgcn_mfma_f32_32x32x16_f16(b0[slot], wf[1][KS], acc[0][1], 0, 0, 0);
        if constexpr (MT == 2) {
            acc[1][0] = __builtin_amdgcn_mfma_f32_32x32x16_f16(b1[slot], wf[0][KS], acc[1][0], 0, 0, 0);
            acc[1][1] = __builtin_amdgcn_mfma_f32_32x32x16_f16(b1[slot], wf[1][KS], acc[1][1], 0, 0, 0);
        }
        if constexpr (KS + 4 < 16) {
            b0[slot] = ldg_llc(a0 + (KS + 4) * 16);
            if constexpr (MT == 2) b1[slot] = ldg_llc(a1 + (KS + 4) * 16);
        }
        KStep<KS + 1, MT>::run(a0, a1, b0, b1, wf, acc);
    }
};
template <int MT>
struct KStep<16, MT> {
    static __device__ __forceinline__ void run(const _Float16*, const _Float16*, half8 (&)[4],
                                               half8 (&)[4], const half8 (&)[2][16],
                                               f32x16 (&)[MT][2]) {}
};

template <int MT>
__device__ __forceinline__ void cell_compute_coh(const _Float16* a0, const _Float16* a1,
                                                 const half8 (&wf)[2][16],
                                                 f32x16 (&acc)[MT][2]) {
#pragma unroll
    for (int mt = 0; mt < MT; ++mt)
#pragma unroll
        for (int nt = 0; nt < 2; ++nt)
#pragma unroll
            for (int r = 0; r < 16; ++r) acc[mt][nt][r] = 0.f;
    half8 b0[4], b1[4];
#pragma unroll
    for (int i = 0; i < 4; ++i) {
        b0[i] = ldg_llc(a0 + i * 16);
        if constexpr (MT == 2) b1[i] = ldg_llc(a1 + i * 16);
    }
    KStep<0, MT>::run(a0, a1, b0, b1, wf, acc);
}

// plain-cached path (layer-0 embedding reads): compiler-scheduled loads
template <int MT>
__device__ __forceinline__ void cell_compute_plain(const _Float16* __restrict__ a0,
                                                   const _Float16* __restrict__ a1,
                                                   const half8 (&wf)[2][16],
                                                   f32x16 (&acc)[MT][2]) {
#pragma unroll
    for (int mt = 0; mt < MT; ++mt)
#pragma unroll
        for (int nt = 0; nt < 2; ++nt)
#pragma unroll
            for (int r = 0; r < 16; ++r) acc[mt][nt][r] = 0.f;
#pragma unroll
    for (int ks = 0; ks < 16; ++ks) {
        half8 x0 = *reinterpret_cast<const half8*>(a0 + ks * 16);
        acc[0][0] = __builtin_amdgcn_mfma_f32_32x32x16_f16(x0, wf[0][ks], acc[0][0], 0, 0, 0);
        acc[0][1] = __builtin_amdgcn_mfma_f32_32x32x16_f16(x0, wf[1][ks], acc[0][1], 0, 0, 0);
        if (MT == 2) {
            half8 x1 = *reinterpret_cast<const half8*>(a1 + ks * 16);
            acc[1][0] = __builtin_amdgcn_mfma_f32_32x32x16_f16(x1, wf[0][ks], acc[1][0], 0, 0, 0);
            acc[1][1] = __builtin_amdgcn_mfma_f32_32x32x16_f16(x1, wf[1][ks], acc[1][1], 0, 0, 0);
        }
    }
}

// part write: C layout (32x32): n=lane&31, m=4*(lane>>5)+(r&3)+8*(r>>2)
template <int MT, bool ADD>
__device__ __forceinline__ void part_write(float (*pw)[64], const f32x16 (&acc)[MT][2],
                                           int lane) {
    const int ln = lane & 31;
#pragma unroll
    for (int mt = 0; mt < MT; ++mt)
#pragma unroll
        for (int nt = 0; nt < 2; ++nt)
#pragma unroll
            for (int r = 0; r < 16; ++r) {
                int m = mt * 32 + 4 * (lane >> 5) + (r & 3) + 8 * (r >> 2);
                int n = nt * 32 + ln;
                int idx = n ^ ((m & 7) << 2);
                if (ADD) pw[m][idx] += acc[mt][nt][r];
                else pw[m][idx] = acc[mt][nt][r];
            }
}

// Persistent wavefront LSTM: 256 blocks x 512 threads (8 waves, 2/SIMD).
// Wave w: K-slice 256 (w<4: y/w_ih, w>=4: h/w_hh), full N=64.
__global__ __launch_bounds__(512, 2) void lstm_persistent(
    const int* __restrict__ padded_in, const int* __restrict__ in_lengths,
    const float* __restrict__ w_ih, const float* __restrict__ w_hh,
    const float* __restrict__ biasf, int* __restrict__ bar,
    const _Float16* __restrict__ ehi, _Float16* __restrict__ hbh,
    _Float16* __restrict__ ybh, float* __restrict__ out) {
    __shared__ __align__(16) float part[4][64][64];  // 64 KB

    const int cu = blockIdx.x;
    const int layer = cu >> 6;
    const int j0 = (cu & 63) * 16;
    const int tid = threadIdx.x;
    const int wv = tid >> 6;
    const int lane = tid & 63;
    const int ln = lane & 31;
    const int khalf = (lane >> 5) * 8;
    const bool isH = (wv >= 4);
    const int kb = (isH ? (wv - 4) : wv) * 256;

    // ---- one-time weight preload: fp32 -> fp16 frags, 128 VGPR/lane
    half8 wf[2][16];
    {
        const float* wsrc = isH ? w_hh : w_ih;
#pragma unroll
        for (int nt = 0; nt < 2; ++nt) {
            int n = nt * 32 + ln;
            const float* rowp =
                wsrc + ((size_t)layer * 4 * Hn + (n >> 4) * Hn + j0 + (n & 15)) * Hn + kb + khalf;
#pragma unroll
            for (int ks = 0; ks < 16; ++ks) {
                f32x4 a = *reinterpret_cast<const f32x4*>(rowp + ks * 16);
                f32x4 b = *reinterpret_cast<const f32x4*>(rowp + ks * 16 + 4);
                half8 h;
                h[0] = (_Float16)a[0]; h[1] = (_Float16)a[1];
                h[2] = (_Float16)a[2]; h[3] = (_Float16)a[3];
                h[4] = (_Float16)b[0]; h[5] = (_Float16)b[1];
                h[6] = (_Float16)b[2]; h[7] = (_Float16)b[3];
                wf[nt][ks] = h;
            }
        }
    }

    // epilogue ownership (threads 0..255): batch row brow, 4 units jcol..jcol+3
    const int brow = (tid & 255) >> 2;
    const int jcol = (tid & 3) * 4;
    float bias[4][4];
#pragma unroll
    for (int g = 0; g < 4; ++g)
#pragma unroll
        for (int p = 0; p < 4; ++p)
            bias[g][p] = biasf[layer * 4096 + g * 1024 + j0 + jcol + p];

    float creg[4] = {0.f, 0.f, 0.f, 0.f};
    float hreg[4] = {0.f, 0.f, 0.f, 0.f};

    for (int w = 0; w < Sn + Ln - 1; ++w) {
        const int t = w - layer;
        if (t >= 0 && t < Sn) {
            const int bs = in_lengths[t];
            const int pin = t & 1;
            const int pout = pin ^ 1;

            // per-wave A-source pointers for its K-slice
            const _Float16 *a0, *a1;
            bool coh;
            if (!isH) {
                const int ko = kb + khalf;
                if (layer == 0) {  // embedding: read-only, cacheable
                    a0 = ehi + (size_t)padded_in[ln * Sn + t] * Hn + ko;
                    a1 = ehi + (size_t)padded_in[(32 + ln) * Sn + t] * Hn + ko;
                    coh = false;
                } else {
                    size_t base = (size_t)(pin * 3 + layer - 1) * BH + ko;
                    a0 = ybh + base + (size_t)ln * Hn;
                    a1 = ybh + base + (size_t)(32 + ln) * Hn;
                    coh = true;
                }
            } else {
                size_t base = (size_t)(pin * Ln + layer) * BH + kb + khalf;
                a0 = hbh + base + (size_t)ln * Hn;
                a1 = hbh + base + (size_t)(32 + ln) * Hn;
                coh = true;
            }

            // compute; two-phase partial accumulation (waves 0-3 store, 4-7 add)
            if (bs > 32) {
                f32x16 acc[2][2];
                if (coh) cell_compute_coh<2>(a0, a1, wf, acc);
                else cell_compute_plain<2>(a0, a1, wf, acc);
                if (wv < 4) part_write<2, false>(part[wv], acc, lane);
                __syncthreads();
                if (wv >= 4) part_write<2, true>(part[wv - 4], acc, lane);
            } else {
                f32x16 acc[1][2];
                if (coh) cell_compute_coh<1>(a0, a1, wf, acc);
                else cell_compute_plain<1>(a0, a1, wf, acc);
                if (wv < 4) part_write<1, false>(part[wv], acc, lane);
                __syncthreads();
                if (wv >= 4) part_write<1, true>(part[wv - 4], acc, lane);
            }
            __syncthreads();

            if (tid < 256) {
                // cross-wave K-reduction + bias
                float gsum[4][4];
#pragma unroll
                for (int g = 0; g < 4; ++g) {
                    int nidx = (g * 16 + jcol) ^ ((brow & 7) << 2);
                    f32x4 s = *reinterpret_cast<const f32x4*>(&part[0][brow][nidx]);
#pragma unroll
                    for (int p2 = 1; p2 < 4; ++p2)
                        s = s + *reinterpret_cast<const f32x4*>(&part[p2][brow][nidx]);
#pragma unroll
                    for (int p = 0; p < 4; ++p) gsum[g][p] = s[p] + bias[g][p];
                }

                const bool active = (brow < bs);
                const int J = j0 + jcol;
                float hold[4], ysum[4];
#pragma unroll
                for (int p = 0; p < 4; ++p) {
                    float cn = sigmf(gsum[1][p]) * creg[p] + sigmf(gsum[0][p]) * tanhf_(gsum[2][p]);
                    float hn = sigmf(gsum[3][p]) * tanhf_(cn);
                    hold[p] = hreg[p];
                    if (active) { creg[p] = cn; hreg[p] = hn; }
                    ysum[p] = hreg[p] + hold[p];
                }
                {   // h broadcast (fp16, t-parity double buffer) -> LLC
                    half4v hh;
#pragma unroll
                    for (int p = 0; p < 4; ++p) hh[p] = (_Float16)hreg[p];
                    stg_coh4(&hbh[((size_t)(pout * Ln + layer) * Bn + brow) * Hn + J], hh);
                }
                if (layer < 3) {  // y interface feed (same-parity slot) -> LLC
                    half4v yh;
                    if (active) {
#pragma unroll
                        for (int p = 0; p < 4; ++p) yh[p] = (_Float16)ysum[p];
                    } else {  // carry incoming y (x_t for l=0) verbatim
                        if (layer == 0) {
                            int ib = padded_in[brow * Sn + t];
                            yh = *reinterpret_cast<const half4v*>(&ehi[(size_t)ib * Hn + J]);
                        } else {
                            yh = ldg_coh4(&ybh[((size_t)(pin * 3 + layer - 1) * Bn + brow) * Hn + J]);
                        }
                    }
                    stg_coh4(&ybh[((size_t)(pin * 3 + layer) * Bn + brow) * Hn + J], yh);
                }
            }
        }
        grid_barrier(bar, cu);
    }

    if (layer == 3 && tid < 256) {
        f32x4 o;
#pragma unroll
        for (int p = 0; p < 4; ++p) o[p] = hreg[p];
        *reinterpret_cast<f32x4*>(&out[(size_t)brow * Hn + j0 + jcol]) = o;
    }
}

extern "C" void kernel_launch(void* const* d_in, const int* in_sizes, int n_in,
                              void* d_out, int out_size, void* d_ws, size_t ws_size,
                              hipStream_t stream) {
    const int* padded_in = (const int*)d_in[0];
    const int* in_lengths = (const int*)d_in[1];
    const float* emb = (const float*)d_in[2];
    const float* w_ih = (const float*)d_in[3];
    const float* w_hh = (const float*)d_in[4];
    const float* b_ih = (const float*)d_in[5];
    const float* b_hh = (const float*)d_in[6];
    float* outp = (float*)d_out;

    // workspace (~2 MB), all segments 16B-aligned
    char* w = (char*)d_ws;
    int* bar = (int*)w;            w += BAR_INTS * 4;
    float* biasf = (float*)w;      w += (size_t)Ln * 4 * Hn * 4;
    _Float16* ehi = (_Float16*)w;  w += (size_t)Vn * Hn * 2;
    _Float16* hbh = (_Float16*)w;  w += (size_t)2 * Ln * Bn * Hn * 2;
    _Float16* ybh = (_Float16*)w;  w += (size_t)2 * 3 * Bn * Hn * 2;

    init_kernel<<<256, 256, 0, stream>>>(b_ih, b_hh, emb, bar, biasf, ehi, hbh);
    lstm_persistent<<<NBLK, 512, 0, stream>>>(padded_in, in_lengths, w_ih, w_hh, biasf, bar,
                                              ehi, hbh, ybh, outp);
}